// Round 13
// baseline (139.136 us; speedup 1.0000x reference)
//
#include <hip/hip_runtime.h>
#include <hip/hip_cooperative_groups.h>
#include <hip/hip_bf16.h>
#include <math.h>

namespace cg = cooperative_groups;

#define NB   4      // batch
#define CIN  128
#define C    64
#define HH   64
#define WW   64
#define HW   4096
#define C8   8
#define RR   4
#define TWOC 128
#define LOG2E 1.44269504088896340736f
#define NBLK 256

typedef __attribute__((ext_vector_type(8))) short short8;
typedef __attribute__((ext_vector_type(4))) float f32x4;
typedef __attribute__((ext_vector_type(16))) float f32x16;
typedef __attribute__((ext_vector_type(4))) int int4v;
typedef __attribute__((ext_vector_type(2))) unsigned uint2v;

__device__ inline ushort f2bf(float f) {
    union { float f; unsigned u; } x{ f };
    unsigned r = x.u + 0x7FFFu + ((x.u >> 16) & 1u);   // RNE
    return (ushort)(r >> 16);
}

__device__ inline float fexp2(float x) { return __builtin_amdgcn_exp2f(x); }

__device__ inline short8 cvt8(f32x4 a, f32x4 b) {
    union { int i[4]; short8 s; } u;
    asm("v_cvt_pk_bf16_f32 %0, %1, %2" : "=v"(u.i[0]) : "v"(a[0]), "v"(a[1]));
    asm("v_cvt_pk_bf16_f32 %0, %1, %2" : "=v"(u.i[1]) : "v"(a[2]), "v"(a[3]));
    asm("v_cvt_pk_bf16_f32 %0, %1, %2" : "=v"(u.i[2]) : "v"(b[0]), "v"(b[1]));
    asm("v_cvt_pk_bf16_f32 %0, %1, %2" : "=v"(u.i[3]) : "v"(b[2]), "v"(b[3]));
    return u.s;
}

struct CafArgs {
    const float *sw, *rn, *pw, *pb, *w1, *w2, *saw, *bsa;
    const float *qw, *qbv, *kw, *kbv, *vw, *vbv, *gammap, *rw, *rb, *sc, *bi;
    float *out, *s_t, *r_t, *cross_t, *part, *cab, *avgc, *maxc, *sab, *part2;
    ushort *q_t, *k_t, *v_t;
};

__global__ __launch_bounds__(512) void caf_mega(CafArgs a)
{
    __shared__ __align__(16) char smem[69632];
    cg::grid_group grid = cg::this_grid();
    const int t = threadIdx.x;
    const int bid = blockIdx.x;
    const float gma = a.gammap[0];
    const bool g0 = (gma == 0.f);

    // ================= P1: proj conv1x1 MFMA + fused stats =================
    {
        const int grp = t >> 8, tl = t & 255;
        const int tile = grp * 256 + bid;
        const int hwT = tile & 63, b = (tile >> 6) & 3, img = tile >> 8;
        const bool active = !(g0 && img == 1);
        ushort* xt  = (ushort*)(smem + grp * 17920);          // [64][132]
        float* redc = (float*)(smem + grp * 17920 + 16896);   // [4][64]
        const int hw0 = hwT << 6;
        const float* x = (img ? a.rn : a.sw) + (size_t)b * CIN * HW + hw0;
        float* y = (img ? a.r_t : a.s_t) + (size_t)b * HW * C;
        if (active) {
            int hwl = tl & 63, cq = tl >> 6;
            #pragma unroll
            for (int i = 0; i < 16; ++i) {
                int c = cq * 32 + i * 2;
                float v1 = x[(size_t)c * HW + hwl];
                float v2 = x[(size_t)(c + 1) * HW + hwl];
                int pk;
                asm("v_cvt_pk_bf16_f32 %0, %1, %2" : "=v"(pk) : "v"(v1), "v"(v2));
                *(unsigned*)&xt[hwl * 132 + c] = (unsigned)pk;
            }
        }
        __syncthreads();
        if (active) {
            int lane = tl & 63, wv = tl >> 6;
            int colL = lane & 15, g = lane >> 4;
            int hwsub = wv << 4;
            f32x4 acc[4] = {};
            #pragma unroll
            for (int ks = 0; ks < 4; ++ks) {
                const ushort* ap = &xt[(hwsub + colL) * 132 + ks * 32 + g * 8];
                union { uint2 u2[2]; short8 s; } af;
                af.u2[0] = *(const uint2*)ap;
                af.u2[1] = *(const uint2*)(ap + 4);
                #pragma unroll
                for (int ot = 0; ot < 4; ++ot) {
                    const float* wp = a.pw + (size_t)(ot * 16 + colL) * CIN + ks * 32 + g * 8;
                    short8 bf = cvt8(*(const f32x4*)wp, *(const f32x4*)(wp + 4));
                    acc[ot] = __builtin_amdgcn_mfma_f32_16x16x32_bf16(af.s, bf, acc[ot], 0, 0, 0);
                }
            }
            float rowsum[4], rowmax[4], colsum[4];
            #pragma unroll
            for (int r = 0; r < 4; ++r) { rowsum[r] = 0.f; rowmax[r] = -1e30f; }
            #pragma unroll
            for (int ot = 0; ot < 4; ++ot) colsum[ot] = 0.f;
            #pragma unroll
            for (int ot = 0; ot < 4; ++ot) {
                float bb = a.pb[ot * 16 + colL];
                #pragma unroll
                for (int r = 0; r < 4; ++r) {
                    float v = acc[ot][r] + bb;
                    y[(size_t)(hw0 + hwsub + g * 4 + r) * C + ot * 16 + colL] = v;
                    rowsum[r] += v;
                    rowmax[r] = fmaxf(rowmax[r], v);
                    colsum[ot] += v;
                }
            }
            #pragma unroll
            for (int d = 1; d < 16; d <<= 1) {
                #pragma unroll
                for (int r = 0; r < 4; ++r) {
                    rowsum[r] += __shfl_xor(rowsum[r], d);
                    rowmax[r] = fmaxf(rowmax[r], __shfl_xor(rowmax[r], d));
                }
            }
            if (colL == 0) {
                int ob = (img * 4 + b) * HW + hw0 + hwsub + g * 4;
                #pragma unroll
                for (int r = 0; r < 4; ++r) {
                    a.avgc[ob + r] = rowsum[r] * (1.f / C);
                    a.maxc[ob + r] = rowmax[r];
                }
            }
            #pragma unroll
            for (int d = 16; d < 64; d <<= 1) {
                #pragma unroll
                for (int ot = 0; ot < 4; ++ot) colsum[ot] += __shfl_xor(colsum[ot], d);
            }
            if (g == 0) {
                #pragma unroll
                for (int ot = 0; ot < 4; ++ot) redc[wv * 64 + ot * 16 + colL] = colsum[ot];
            }
        }
        __syncthreads();
        if (active && tl < 64)
            a.part[((size_t)(img * 4 + b) * 64 + hwT) * 64 + tl] =
                redc[tl] + redc[64 + tl] + redc[128 + tl] + redc[192 + tl];
    }
    grid.sync();

    // ================= P2: channel-attn MLP (block 64) + spatial-attn conv (blocks 0..63) =================
    if (bid == 64) {
        float* avs = (float*)smem;            // [8][64]
        float* hsh = (float*)(smem + 2048);   // [8][4]
        {
            int c = t & 63, ib = t >> 6;
            float avg = 0.f;
            for (int hwT = 0; hwT < 64; ++hwT)
                avg += a.part[((size_t)ib * 64 + hwT) * 64 + c];
            avs[ib * 64 + c] = avg * (1.f / HW);
        }
        __syncthreads();
        if (t < 32) {
            int ib2 = t >> 2, r = t & 3;
            float acc = 0.f;
            for (int cc = 0; cc < C; ++cc) acc += avs[ib2 * 64 + cc] * a.w1[r * C + cc];
            hsh[ib2 * 4 + r] = fmaxf(acc, 0.f);
        }
        __syncthreads();
        {
            int c = t & 63, ib = t >> 6;
            float acc = 0.f;
            #pragma unroll
            for (int r = 0; r < RR; ++r) acc += hsh[ib * 4 + r] * a.w2[c * RR + r];
            a.cab[ib * 64 + c] = 1.f / (1.f + __expf(-acc));
        }
    } else if (bid < 64) {
        float* wsh = (float*)smem;            // [98]
        if (t < 98) wsh[t] = a.saw[t];
        __syncthreads();
        int idx = bid * 512 + t;              // 0..32767 over 8 ib x 4096 hw
        int ib = idx >> 12, hw = idx & 4095;
        if (!(g0 && ib >= 4)) {
            int base = ib * HW;
            int y0 = hw >> 6, x0 = hw & 63;
            float acc = a.bsa[0];
            for (int dy = -3; dy <= 3; ++dy) {
                int yy = y0 + dy; if (yy < 0 || yy >= HH) continue;
                for (int dx = -3; dx <= 3; ++dx) {
                    int xx = x0 + dx; if (xx < 0 || xx >= WW) continue;
                    int widx = (dy + 3) * 7 + (dx + 3);
                    int p = base + yy * WW + xx;
                    acc += a.avgc[p] * wsh[widx] + a.maxc[p] * wsh[49 + widx];
                }
            }
            a.sab[base + hw] = 1.f / (1.f + __expf(-acc));
        }
    }
    grid.sync();

    // ================= P3+P4: attention path (gamma != 0 only; skipped uniformly) =================
    if (!g0) {
        // ---- P3: q/k/v projections, gates inline ----
        {
            float* wshv = (float*)smem;             // [64][64]
            float* qsh = (float*)(smem + 16384);    // [8][64]
            float* ksh = (float*)(smem + 18432);    // [8][64]
            for (int i = t; i < 4096; i += 512) wshv[i] = a.vw[i];
            if (t < 512) { qsh[t] = a.qw[t]; ksh[t] = a.kw[t]; }
            __syncthreads();
            if (t < 256) {
                int hw = ((bid & 63) << 6) + (t & 63);
                int b  = bid >> 6;
                int qt = t >> 6;
                int c0 = qt << 4;
                const float* erp = a.r_t + (size_t)(b * HW + hw) * C;
                const float* esp = a.s_t + (size_t)(b * HW + hw) * C;
                const float* cas = a.cab + b * 64;
                const float* car = a.cab + (4 + b) * 64;
                float gs = a.sab[b * HW + hw];
                float gr = a.sab[(4 + b) * HW + hw];
                float va[16];
                #pragma unroll
                for (int j = 0; j < 16; ++j) va[j] = a.vbv[c0 + j];
                float qa[8], ka[8];
                #pragma unroll
                for (int o = 0; o < 8; ++o) { qa[o] = a.qbv[o]; ka[o] = a.kbv[o]; }
                #pragma unroll 4
                for (int i = 0; i < 16; ++i) {
                    f32x4 xr = *(const f32x4*)(erp + i * 4) * *(const f32x4*)(car + i * 4) * gr;
                    #pragma unroll
                    for (int j = 0; j < 16; ++j) {
                        const float* wr = &wshv[(c0 + j) * 64 + i * 4];
                        va[j] += xr[0]*wr[0] + xr[1]*wr[1] + xr[2]*wr[2] + xr[3]*wr[3];
                    }
                    if (qt == 0) {
                        f32x4 xs = *(const f32x4*)(esp + i * 4) * *(const f32x4*)(cas + i * 4) * gs;
                        #pragma unroll
                        for (int o = 0; o < 8; ++o) {
                            const float* wr = &qsh[o * 64 + i * 4];
                            qa[o] += xs[0]*wr[0] + xs[1]*wr[1] + xs[2]*wr[2] + xs[3]*wr[3];
                        }
                    } else if (qt == 3) {
                        #pragma unroll
                        for (int o = 0; o < 8; ++o) {
                            const float* wr = &ksh[o * 64 + i * 4];
                            ka[o] += xr[0]*wr[0] + xr[1]*wr[1] + xr[2]*wr[2] + xr[3]*wr[3];
                        }
                    }
                }
                #pragma unroll
                for (int j = 0; j < 16; ++j)
                    a.v_t[((size_t)(b * C + c0 + j) << 12) + hw] = f2bf(va[j]);
                if (qt == 0) {
                    union { ushort u[8]; int4v v; } qo;
                    #pragma unroll
                    for (int o = 0; o < 8; ++o) qo.u[o] = f2bf(qa[o] * LOG2E);
                    *(int4v*)(a.q_t + (size_t)(b * HW + hw) * 8) = qo.v;
                } else if (qt == 3) {
                    union { ushort u[8]; int4v v; } ko;
                    #pragma unroll
                    for (int o = 0; o < 8; ++o) ko.u[o] = f2bf(ka[o]);
                    *(int4v*)(a.k_t + (size_t)(b * HW + hw) * 8) = ko.v;
                }
            }
        }
        grid.sync();

        // ---- P4: flash cross-attention (2 jobs per block) ----
        float* paccs = (float*)smem;               // [8][64][33]
        float* pml   = (float*)(smem + 67584);     // [8][2][32]
        for (int rep = 0; rep < 2; ++rep) {
            int job = bid * 2 + rep;               // 0..511
            const int lane = t & 63;
            const int ws2  = t >> 6;
            const int b    = job >> 7;
            const int n0   = (job & 127) << 5;
            const int l31  = lane & 31;
            const int h    = lane >> 5;
            short8 qf = short8(0);
            if (lane < 32) qf = *(const short8*)(a.q_t + ((size_t)(b * HW) + n0 + l31) * 8);
            f32x16 acc0 = (f32x16)(0.f), acc1 = (f32x16)(0.f);
            float mrun = -1e30f, lrun = 0.f;
            const ushort* kbase = a.k_t + (size_t)(b * HW) * 8;
            const ushort* vb0 = a.v_t + ((size_t)(b * C) + l31) * HW + 8 * h;
            const ushort* vb1 = a.v_t + ((size_t)(b * C) + 32 + l31) * HW + 8 * h;
            const int mbeg = ws2 << 9, mend = mbeg + 512;
            for (int m0 = mbeg; m0 < mend; m0 += 32) {
                short8 kf = short8(0);
                if (lane < 32) kf = *(const short8*)(kbase + ((size_t)(m0 + l31)) * 8);
                short8 v00 = *(const short8*)(vb0 + m0);
                short8 v01 = *(const short8*)(vb0 + m0 + 16);
                short8 v10 = *(const short8*)(vb1 + m0);
                short8 v11 = *(const short8*)(vb1 + m0 + 16);
                f32x16 s = __builtin_amdgcn_mfma_f32_32x32x16_bf16(kf, qf, (f32x16)(0.f), 0, 0, 0);
                float t0 = fmaxf(fmaxf(s[0], s[1]), fmaxf(s[2], s[3]));
                float t1 = fmaxf(fmaxf(s[4], s[5]), fmaxf(s[6], s[7]));
                float t2 = fmaxf(fmaxf(s[8], s[9]), fmaxf(s[10], s[11]));
                float t3 = fmaxf(fmaxf(s[12], s[13]), fmaxf(s[14], s[15]));
                float tmax = fmaxf(fmaxf(t0, t1), fmaxf(t2, t3));
                tmax = fmaxf(tmax, __shfl_xor(tmax, 32));
                if (!__all(tmax <= mrun)) {
                    float mnew = fmaxf(mrun, tmax);
                    float corr = fexp2(mrun - mnew);
                    lrun *= corr;
                    acc0 *= corr;
                    acc1 *= corr;
                    mrun = mnew;
                }
                float p[16];
                #pragma unroll
                for (int r = 0; r < 16; ++r) p[r] = fexp2(s[r] - mrun);
                float ts = ((p[0]+p[1]) + (p[2]+p[3])) + ((p[4]+p[5]) + (p[6]+p[7]))
                         + ((p[8]+p[9]) + (p[10]+p[11])) + ((p[12]+p[13]) + (p[14]+p[15]));
                ts += __shfl_xor(ts, 32);
                lrun += ts;
                int c01, c23, c45, c67, c89, cAB, cCD, cEF;
                asm("v_cvt_pk_bf16_f32 %0, %1, %2" : "=v"(c01) : "v"(p[0]),  "v"(p[1]));
                asm("v_cvt_pk_bf16_f32 %0, %1, %2" : "=v"(c23) : "v"(p[2]),  "v"(p[3]));
                asm("v_cvt_pk_bf16_f32 %0, %1, %2" : "=v"(c45) : "v"(p[4]),  "v"(p[5]));
                asm("v_cvt_pk_bf16_f32 %0, %1, %2" : "=v"(c67) : "v"(p[6]),  "v"(p[7]));
                asm("v_cvt_pk_bf16_f32 %0, %1, %2" : "=v"(c89) : "v"(p[8]),  "v"(p[9]));
                asm("v_cvt_pk_bf16_f32 %0, %1, %2" : "=v"(cAB) : "v"(p[10]), "v"(p[11]));
                asm("v_cvt_pk_bf16_f32 %0, %1, %2" : "=v"(cCD) : "v"(p[12]), "v"(p[13]));
                asm("v_cvt_pk_bf16_f32 %0, %1, %2" : "=v"(cEF) : "v"(p[14]), "v"(p[15]));
                uint2v s1 = __builtin_amdgcn_permlane32_swap(c45, c01, false, false);
                uint2v s2 = __builtin_amdgcn_permlane32_swap(c67, c23, false, false);
                uint2v s3 = __builtin_amdgcn_permlane32_swap(cCD, c89, false, false);
                uint2v s4 = __builtin_amdgcn_permlane32_swap(cEF, cAB, false, false);
                union { unsigned u[4]; short8 s; } B0, B1;
                B0.u[0] = s1[1]; B0.u[1] = s2[1]; B0.u[2] = s1[0]; B0.u[3] = s2[0];
                B1.u[0] = s3[1]; B1.u[1] = s4[1]; B1.u[2] = s3[0]; B1.u[3] = s4[0];
                acc0 = __builtin_amdgcn_mfma_f32_32x32x16_bf16(v00, B0.s, acc0, 0, 0, 0);
                acc0 = __builtin_amdgcn_mfma_f32_32x32x16_bf16(v01, B1.s, acc0, 0, 0, 0);
                acc1 = __builtin_amdgcn_mfma_f32_32x32x16_bf16(v10, B0.s, acc1, 0, 0, 0);
                acc1 = __builtin_amdgcn_mfma_f32_32x32x16_bf16(v11, B1.s, acc1, 0, 0, 0);
            }
            #pragma unroll
            for (int r = 0; r < 16; ++r) {
                int c = (r & 3) + 8 * (r >> 2) + 4 * h;
                paccs[(ws2 * 64 + c) * 33 + l31]        = acc0[r];
                paccs[(ws2 * 64 + c + 32) * 33 + l31]   = acc1[r];
            }
            if (lane < 32) { pml[(ws2 * 2 + 0) * 32 + l31] = mrun; pml[(ws2 * 2 + 1) * 32 + l31] = lrun; }
            __syncthreads();
            #pragma unroll
            for (int k = 0; k < 4; ++k) {
                int c = t & 63;
                int n = (t >> 6) + 8 * k;
                float M = -1e30f;
                #pragma unroll
                for (int w3 = 0; w3 < 8; ++w3) M = fmaxf(M, pml[(w3 * 2) * 32 + n]);
                float L = 0.f, oacc = 0.f;
                #pragma unroll
                for (int w3 = 0; w3 < 8; ++w3) {
                    float e = fexp2(pml[(w3 * 2) * 32 + n] - M);
                    L += pml[(w3 * 2 + 1) * 32 + n] * e;
                    oacc += paccs[(w3 * 64 + c) * 33 + n] * e;
                }
                size_t idx = ((size_t)(b * HW) + n0 + n) * C + c;
                float esv = a.s_t[idx] * a.cab[b * 64 + c] * a.sab[b * HW + n0 + n];
                a.cross_t[idx] = gma * oacc / L + esv;
            }
            __syncthreads();
        }
        grid.sync();
    }

    // ================= P5: refine MFMA GEMM + BN partials (8-wave split) =================
    {
        int hwT = bid & 63, b = bid >> 6;
        int hw0 = hwT << 6;
        int lane = t & 63, wv = t >> 6;       // 0..7
        int colL = lane & 15, g = lane >> 4;
        int wh = wv & 3, oh = wv >> 2;        // hw-quarter, ot-half
        int hw = hw0 + wh * 16 + colL;
        const float* sp = a.s_t + ((size_t)(b * HW) + hw) * C;
        const float* cp = a.cross_t + ((size_t)(b * HW) + hw) * C;
        const float* cgb = a.cab + b * 64;
        float gate = a.sab[b * HW + hw];
        float* redp = (float*)smem;           // [8][64][2]
        f32x4 acc[4] = {};
        #pragma unroll
        for (int ks = 0; ks < 4; ++ks) {
            f32x4 x1, x2;
            if (ks < 2 && !g0) {
                const float* src = cp + (ks & 1) * 32 + g * 8;
                x1 = *(const f32x4*)src;
                x2 = *(const f32x4*)(src + 4);
            } else {
                const float* src = sp + (ks & 1) * 32 + g * 8;
                const float* cg = cgb + (ks & 1) * 32 + g * 8;
                x1 = *(const f32x4*)src * *(const f32x4*)cg * gate;
                x2 = *(const f32x4*)(src + 4) * *(const f32x4*)(cg + 4) * gate;
            }
            short8 bf = cvt8(x1, x2);
            #pragma unroll
            for (int ot2 = 0; ot2 < 4; ++ot2) {
                int ot = oh * 4 + ot2;
                const float* ap = a.rw + (size_t)(ot * 16 + colL) * TWOC + ks * 32 + g * 8;
                short8 afr = cvt8(*(const f32x4*)ap, *(const f32x4*)(ap + 4));
                acc[ot2] = __builtin_amdgcn_mfma_f32_16x16x32_bf16(afr, bf, acc[ot2], 0, 0, 0);
            }
        }
        #pragma unroll
        for (int ot2 = 0; ot2 < 4; ++ot2) {
            int ot = oh * 4 + ot2;
            int o = ot * 16 + g * 4;
            #pragma unroll
            for (int r = 0; r < 4; ++r) {
                float v = acc[ot2][r] + a.rb[o + r];
                a.out[((size_t)(b * TWOC + o + r) << 12) + hw] = v;
                float vq = v * v;
                #pragma unroll
                for (int d = 1; d < 16; d <<= 1) {
                    v  += __shfl_xor(v, d);
                    vq += __shfl_xor(vq, d);
                }
                if (colL == 0) {
                    int ol = ot2 * 16 + g * 4 + r;     // 0..63 within oh-half
                    redp[(wv * 64 + ol) * 2 + 0] = v;
                    redp[(wv * 64 + ol) * 2 + 1] = vq;
                }
            }
        }
        __syncthreads();
        if (t < 128) {
            int o = t;
            int ohh = o >> 6, ol = o & 63;
            float s = 0.f, s2 = 0.f;
            #pragma unroll
            for (int w3 = 0; w3 < 4; ++w3) {
                int wvi = ohh * 4 + w3;
                s  += redp[(wvi * 64 + ol) * 2 + 0];
                s2 += redp[(wvi * 64 + ol) * 2 + 1];
            }
            a.part2[o * 256 + bid] = s;
            a.part2[32768 + o * 256 + bid] = s2;
        }
    }
    grid.sync();

    // ================= P6: BN reduce + apply + relu (2 (b,o) pairs per block) =================
    {
        float* rs  = (float*)smem;        // [8]
        float* rs2 = rs + 8;              // [8]
        float* bc  = rs2 + 8;             // [2]
        f32x4* y4 = (f32x4*)a.out;
        for (int rep = 0; rep < 2; ++rep) {
            int bo = bid * 2 + rep;       // 0..511
            int o = bo & 127;
            float s = 0.f, s2 = 0.f;
            if (t < 256) { s = a.part2[o * 256 + t]; s2 = a.part2[32768 + o * 256 + t]; }
            for (int d = 32; d > 0; d >>= 1) { s += __shfl_down(s, d); s2 += __shfl_down(s2, d); }
            if ((t & 63) == 0) { rs[t >> 6] = s; rs2[t >> 6] = s2; }
            __syncthreads();
            if (t == 0) {
                float S  = rs[0] + rs[1] + rs[2] + rs[3];
                float S2 = rs2[0] + rs2[1] + rs2[2] + rs2[3];
                float m = S * (1.f / (NB * HW));
                float var = S2 * (1.f / (NB * HW)) - m * m;
                bc[0] = m;
                bc[1] = rsqrtf(var + 1e-5f);
            }
            __syncthreads();
            float m = bc[0], rstd = bc[1], scale = a.sc[o], bias = a.bi[o];
            #pragma unroll
            for (int k = 0; k < 2; ++k) {
                size_t i4 = (size_t)bo * 1024 + t + k * 512;
                f32x4 v = y4[i4];
                #pragma unroll
                for (int j = 0; j < 4; ++j) v[j] = fmaxf((v[j] - m) * rstd * scale + bias, 0.f);
                y4[i4] = v;
            }
            __syncthreads();
        }
    }
}

extern "C" void kernel_launch(void* const* d_in, const int* in_sizes, int n_in,
                              void* d_out, int out_size, void* d_ws, size_t ws_size,
                              hipStream_t stream) {
    float* ws = (float*)d_ws;
    float* s_t    = ws;                  // 1048576
    float* r_t    = s_t + 1048576;       // 1048576
    float* cross_t= r_t + 1048576;       // 1048576
    float* part   = cross_t + 1048576;   // 32768
    float* cab    = part + 32768;        // 512
    float* avgc   = cab + 512;           // 32768
    float* maxc   = avgc + 32768;        // 32768
    float* sab    = maxc + 32768;        // 32768
    float* part2  = sab + 32768;         // 65536
    ushort* q_t   = (ushort*)(part2 + 65536); // 131072 us
    ushort* k_t   = q_t + 131072;             // 131072 us
    ushort* v_t   = k_t + 131072;             // 1048576 us

    CafArgs a;
    a.sw  = (const float*)d_in[0];  a.rn  = (const float*)d_in[1];
    a.pw  = (const float*)d_in[2];  a.pb  = (const float*)d_in[3];
    a.w1  = (const float*)d_in[4];  a.w2  = (const float*)d_in[5];
    a.saw = (const float*)d_in[6];  a.bsa = (const float*)d_in[7];
    a.qw  = (const float*)d_in[8];  a.qbv = (const float*)d_in[9];
    a.kw  = (const float*)d_in[10]; a.kbv = (const float*)d_in[11];
    a.vw  = (const float*)d_in[12]; a.vbv = (const float*)d_in[13];
    a.gammap = (const float*)d_in[14];
    a.rw  = (const float*)d_in[15]; a.rb  = (const float*)d_in[16];
    a.sc  = (const float*)d_in[17]; a.bi  = (const float*)d_in[18];
    a.out = (float*)d_out;
    a.s_t = s_t; a.r_t = r_t; a.cross_t = cross_t;
    a.part = part; a.cab = cab; a.avgc = avgc; a.maxc = maxc; a.sab = sab;
    a.part2 = part2; a.q_t = q_t; a.k_t = k_t; a.v_t = v_t;

    void* kp[] = { (void*)&a };
    (void)hipLaunchCooperativeKernel((const void*)caf_mega, dim3(NBLK), dim3(512),
                                     kp, 0, stream);
}

// Round 14
// 45.291 us; speedup vs baseline: 3.0721x; 3.0721x over previous
//
#include <hip/hip_runtime.h>
#include <hip/hip_bf16.h>
#include <math.h>

#define NB   4      // batch
#define CIN  128
#define C    64
#define HH   64
#define WW   64
#define HW   4096
#define C8   8
#define RR   4
#define TWOC 128
#define LOG2E 1.44269504088896340736f

typedef __attribute__((ext_vector_type(8))) short short8;
typedef __attribute__((ext_vector_type(4))) float f32x4;
typedef __attribute__((ext_vector_type(16))) float f32x16;
typedef __attribute__((ext_vector_type(4))) int int4v;
typedef __attribute__((ext_vector_type(2))) unsigned uint2v;

__device__ inline ushort f2bf(float f) {
    union { float f; unsigned u; } x{ f };
    unsigned r = x.u + 0x7FFFu + ((x.u >> 16) & 1u);   // RNE
    return (ushort)(r >> 16);
}

// hazard-safe HW exp2 (TRANS op via intrinsic so the backend inserts wait-states)
__device__ inline float fexp2(float x) { return __builtin_amdgcn_exp2f(x); }

// pack 8 f32 -> 8 bf16 (RNE) as a short8 MFMA fragment
__device__ inline short8 cvt8(f32x4 a, f32x4 b) {
    union { int i[4]; short8 s; } u;
    asm("v_cvt_pk_bf16_f32 %0, %1, %2" : "=v"(u.i[0]) : "v"(a[0]), "v"(a[1]));
    asm("v_cvt_pk_bf16_f32 %0, %1, %2" : "=v"(u.i[1]) : "v"(a[2]), "v"(a[3]));
    asm("v_cvt_pk_bf16_f32 %0, %1, %2" : "=v"(u.i[2]) : "v"(b[0]), "v"(b[1]));
    asm("v_cvt_pk_bf16_f32 %0, %1, %2" : "=v"(u.i[3]) : "v"(b[2]), "v"(b[3]));
    return u.s;
}

// ---------------- proj conv1x1 MFMA GEMM + fused stats epilogue ----------------
// Also pre-converts refine weights to bf16 (32 floats/block, before gamma gate).
__global__ __launch_bounds__(256) void proj_gemm_kernel(
    const float* __restrict__ sw, const float* __restrict__ rn,
    const float* __restrict__ w, const float* __restrict__ bias,
    const float* __restrict__ gammap, const float* __restrict__ rw,
    float* __restrict__ s_t, float* __restrict__ r_t,
    float* __restrict__ part, float* __restrict__ avgc, float* __restrict__ maxc,
    ushort* __restrict__ rwb) {
    int bid = blockIdx.x;
    int t = threadIdx.x;
    // refine-weight bf16 pre-conversion: 512 blocks x 32 floats = 16384
    if (t < 32) rwb[bid * 32 + t] = f2bf(rw[bid * 32 + t]);

    int hwT = bid & 63;
    int b   = (bid >> 6) & 3;
    int img = bid >> 8;
    if (img == 1 && gammap[0] == 0.f) return;
    int hw0 = hwT << 6;
    const float* x = (img ? rn : sw) + (size_t)b * CIN * HW + hw0;
    float* y = (img ? r_t : s_t) + (size_t)b * HW * C;

    __shared__ ushort xt[64 * 132];   // [hw][128c + 4 pad]
    __shared__ float redc[4][64];
    {
        // pair-staging: two adjacent channels are LDS-contiguous -> 1 cvt_pk + b32 store
        int hwl = t & 63, cq = t >> 6;
        #pragma unroll
        for (int i = 0; i < 16; ++i) {
            int c = cq * 32 + i * 2;
            float a  = x[(size_t)c * HW + hwl];
            float b2 = x[(size_t)(c + 1) * HW + hwl];
            int pk;
            asm("v_cvt_pk_bf16_f32 %0, %1, %2" : "=v"(pk) : "v"(a), "v"(b2));
            *(unsigned*)&xt[hwl * 132 + c] = (unsigned)pk;
        }
    }
    __syncthreads();

    int lane = t & 63, wv = t >> 6;
    int colL = lane & 15, g = lane >> 4;
    int hwsub = wv << 4;
    f32x4 acc[4] = {};
    #pragma unroll
    for (int ks = 0; ks < 4; ++ks) {
        const ushort* ap = &xt[(hwsub + colL) * 132 + ks * 32 + g * 8];
        union { uint2 u2[2]; short8 s; } af;
        af.u2[0] = *(const uint2*)ap;
        af.u2[1] = *(const uint2*)(ap + 4);
        #pragma unroll
        for (int ot = 0; ot < 4; ++ot) {
            const float* wp = w + (size_t)(ot * 16 + colL) * CIN + ks * 32 + g * 8;
            short8 bf = cvt8(*(const f32x4*)wp, *(const f32x4*)(wp + 4));
            acc[ot] = __builtin_amdgcn_mfma_f32_16x16x32_bf16(af.s, bf, acc[ot], 0, 0, 0);
        }
    }

    // store + in-register stats
    float rowsum[4], rowmax[4], colsum[4];
    #pragma unroll
    for (int r = 0; r < 4; ++r) { rowsum[r] = 0.f; rowmax[r] = -1e30f; }
    #pragma unroll
    for (int ot = 0; ot < 4; ++ot) colsum[ot] = 0.f;
    #pragma unroll
    for (int ot = 0; ot < 4; ++ot) {
        float bb = bias[ot * 16 + colL];
        #pragma unroll
        for (int r = 0; r < 4; ++r) {
            float v = acc[ot][r] + bb;
            y[(size_t)(hw0 + hwsub + g * 4 + r) * C + ot * 16 + colL] = v;
            rowsum[r] += v;
            rowmax[r] = fmaxf(rowmax[r], v);
            colsum[ot] += v;
        }
    }
    // per-hw reduce over channels (16 colL lanes within g-group)
    #pragma unroll
    for (int d = 1; d < 16; d <<= 1) {
        #pragma unroll
        for (int r = 0; r < 4; ++r) {
            rowsum[r] += __shfl_xor(rowsum[r], d);
            rowmax[r] = fmaxf(rowmax[r], __shfl_xor(rowmax[r], d));
        }
    }
    if (colL == 0) {
        int ob = (img * 4 + b) * HW + hw0 + hwsub + g * 4;
        #pragma unroll
        for (int r = 0; r < 4; ++r) {
            avgc[ob + r] = rowsum[r] * (1.f / C);
            maxc[ob + r] = rowmax[r];
        }
    }
    // per-channel reduce over hw: g (xor 16,32), then cross-wave via LDS
    #pragma unroll
    for (int d = 16; d < 64; d <<= 1) {
        #pragma unroll
        for (int ot = 0; ot < 4; ++ot) colsum[ot] += __shfl_xor(colsum[ot], d);
    }
    if (g == 0) {
        #pragma unroll
        for (int ot = 0; ot < 4; ++ot) redc[wv][ot * 16 + colL] = colsum[ot];
    }
    __syncthreads();
    if (t < 64)
        part[((size_t)(img * 4 + b) * 64 + hwT) * 64 + t] =
            redc[0][t] + redc[1][t] + redc[2][t] + redc[3][t];
}

// ---------------- merged channel-attn MLP + spatial-attn 7x7 conv ----------------
__global__ __launch_bounds__(256) void casa_kernel(
    const float* __restrict__ part, const float* __restrict__ w1,
    const float* __restrict__ w2, float* __restrict__ cab,
    const float* __restrict__ avgc, const float* __restrict__ maxc,
    const float* __restrict__ saw, const float* __restrict__ bsa,
    const float* __restrict__ gammap, float* __restrict__ sab) {
    int bid = blockIdx.x;
    int t = threadIdx.x;
    if (bid == 128) {
        __shared__ float avs[8][64];
        __shared__ float hsh[8][RR];
        #pragma unroll
        for (int it = 0; it < 2; ++it) {
            int idx = t + it * 256;
            int c = idx & 63, ib = idx >> 6;
            float avg = 0.f;
            for (int hwT = 0; hwT < 64; ++hwT)
                avg += part[((size_t)ib * 64 + hwT) * 64 + c];
            avs[ib][c] = avg * (1.f / HW);
        }
        __syncthreads();
        if (t < 32) {
            int ib2 = t >> 2, r = t & 3;
            float a = 0.f;
            for (int cc = 0; cc < C; ++cc) a += avs[ib2][cc] * w1[r * C + cc];
            hsh[ib2][r] = fmaxf(a, 0.f);
        }
        __syncthreads();
        #pragma unroll
        for (int it = 0; it < 2; ++it) {
            int idx = t + it * 256;
            int c = idx & 63, ib = idx >> 6;
            float a = 0.f;
            #pragma unroll
            for (int r = 0; r < RR; ++r) a += hsh[ib][r] * w2[c * RR + r];
            cab[ib * 64 + c] = 1.f / (1.f + __expf(-a));
        }
        return;
    }
    int img = bid >> 6;
    if (img == 1 && gammap[0] == 0.f) return;
    __shared__ float wsh[98];
    if (t < 98) wsh[t] = saw[t];
    __syncthreads();
    int idx = (bid & 63) * 256 + t;            // b*HW + hw
    int b = idx >> 12, hw = idx & 4095;
    int base = (img * 4 + b) * HW;
    int y0 = hw >> 6, x0 = hw & 63;
    float acc = bsa[0];
    for (int dy = -3; dy <= 3; ++dy) {
        int yy = y0 + dy; if (yy < 0 || yy >= HH) continue;
        for (int dx = -3; dx <= 3; ++dx) {
            int xx = x0 + dx; if (xx < 0 || xx >= WW) continue;
            int widx = (dy + 3) * 7 + (dx + 3);
            int p = base + yy * WW + xx;
            acc += avgc[p] * wsh[widx] + maxc[p] * wsh[49 + widx];
        }
    }
    sab[base + hw] = 1.f / (1.f + __expf(-acc));
}

// ---------------- fused q/k/v projections, gates applied inline ----------------
__global__ __launch_bounds__(256) void vqk_proj_kernel(
    const float* __restrict__ es, const float* __restrict__ er,
    const float* __restrict__ vw, const float* __restrict__ vbv,
    const float* __restrict__ qw, const float* __restrict__ qbv,
    const float* __restrict__ kw, const float* __restrict__ kbv,
    const float* __restrict__ gammap,
    const float* __restrict__ cab, const float* __restrict__ sab,
    ushort* __restrict__ v_t, ushort* __restrict__ q_t, ushort* __restrict__ k_t) {
    if (gammap[0] == 0.f) return;     // q/k/v only feed the attention path
    __shared__ float wsh[64][64];            // vw[c][cc]
    __shared__ float qsh[8][64], ksh[8][64]; // qw, kw
    int t = threadIdx.x;
    for (int i = t; i < 4096; i += 256) wsh[i >> 6][i & 63] = vw[i];
    for (int i = t; i < 512; i += 256) qsh[i >> 6][i & 63] = qw[i];
    for (int i = t; i < 512; i += 256) ksh[i >> 6][i & 63] = kw[i];
    __syncthreads();

    int bid = blockIdx.x;
    int hw = ((bid & 63) << 6) + (t & 63);
    int b  = bid >> 6;
    int qt = t >> 6;                 // quarter 0..3
    int c0 = qt << 4;
    const float* erp = er + (size_t)(b * HW + hw) * C;
    const float* esp = es + (size_t)(b * HW + hw) * C;
    const float* cas = cab + b * 64;           // img0 gates
    const float* car = cab + (4 + b) * 64;     // img1 gates
    float gs = sab[b * HW + hw];
    float gr = sab[(4 + b) * HW + hw];

    float va[16];
    #pragma unroll
    for (int j = 0; j < 16; ++j) va[j] = vbv[c0 + j];
    float qa[8], ka[8];
    #pragma unroll
    for (int o = 0; o < 8; ++o) { qa[o] = qbv[o]; ka[o] = kbv[o]; }

    #pragma unroll 4
    for (int i = 0; i < 16; ++i) {
        f32x4 xr = *(const f32x4*)(erp + i * 4) * *(const f32x4*)(car + i * 4) * gr;
        #pragma unroll
        for (int j = 0; j < 16; ++j) {
            const float* wr = &wsh[c0 + j][i * 4];
            va[j] += xr[0]*wr[0] + xr[1]*wr[1] + xr[2]*wr[2] + xr[3]*wr[3];
        }
        if (qt == 0) {
            f32x4 xs = *(const f32x4*)(esp + i * 4) * *(const f32x4*)(cas + i * 4) * gs;
            #pragma unroll
            for (int o = 0; o < 8; ++o) {
                const float* wr = &qsh[o][i * 4];
                qa[o] += xs[0]*wr[0] + xs[1]*wr[1] + xs[2]*wr[2] + xs[3]*wr[3];
            }
        } else if (qt == 3) {
            #pragma unroll
            for (int o = 0; o < 8; ++o) {
                const float* wr = &ksh[o][i * 4];
                ka[o] += xr[0]*wr[0] + xr[1]*wr[1] + xr[2]*wr[2] + xr[3]*wr[3];
            }
        }
    }

    #pragma unroll
    for (int j = 0; j < 16; ++j)
        v_t[((size_t)(b * C + c0 + j) << 12) + hw] = f2bf(va[j]);
    if (qt == 0) {
        union { ushort u[8]; int4v v; } qo;
        #pragma unroll
        for (int o = 0; o < 8; ++o) qo.u[o] = f2bf(qa[o] * LOG2E);
        *(int4v*)(q_t + (size_t)(b * HW + hw) * 8) = qo.v;
    } else if (qt == 3) {
        union { ushort u[8]; int4v v; } ko;
        #pragma unroll
        for (int o = 0; o < 8; ++o) ko.u[o] = f2bf(ka[o]);
        *(int4v*)(k_t + (size_t)(b * HW + hw) * 8) = ko.v;
    }
}

// ---------------- MFMA flash cross-attention v3: 32x32x16, permlane transpose ----------------
__global__ __launch_bounds__(512) void cross_attn_mfma(
    const ushort* __restrict__ q_t, const ushort* __restrict__ k_t,
    const ushort* __restrict__ v_t, const float* __restrict__ es_t,
    const float* __restrict__ gammap,
    const float* __restrict__ cab, const float* __restrict__ sab,
    float* __restrict__ cross_t)
{
    const float gma = gammap[0];
    if (gma == 0.f) return;
    const int tid  = threadIdx.x;
    const int lane = tid & 63;
    const int ws   = tid >> 6;                 // m-split 0..7
    const int b    = blockIdx.x >> 7;          // 128 n-tiles per batch
    const int n0   = (blockIdx.x & 127) << 5;
    const int l31  = lane & 31;
    const int h    = lane >> 5;

    short8 qf = short8(0);
    if (lane < 32) qf = *(const short8*)(q_t + ((size_t)(b * HW) + n0 + l31) * 8);

    f32x16 acc0 = (f32x16)(0.f), acc1 = (f32x16)(0.f);
    float mrun = -1e30f, lrun = 0.f;

    const ushort* kbase = k_t + (size_t)(b * HW) * 8;
    const ushort* vb0 = v_t + ((size_t)(b * C) + l31) * HW + 8 * h;
    const ushort* vb1 = v_t + ((size_t)(b * C) + 32 + l31) * HW + 8 * h;

    const int mbeg = ws << 9, mend = mbeg + 512;
    for (int m0 = mbeg; m0 < mend; m0 += 32) {
        short8 kf = short8(0);
        if (lane < 32) kf = *(const short8*)(kbase + ((size_t)(m0 + l31)) * 8);
        short8 v00 = *(const short8*)(vb0 + m0);
        short8 v01 = *(const short8*)(vb0 + m0 + 16);
        short8 v10 = *(const short8*)(vb1 + m0);
        short8 v11 = *(const short8*)(vb1 + m0 + 16);

        f32x16 s = __builtin_amdgcn_mfma_f32_32x32x16_bf16(kf, qf, (f32x16)(0.f), 0, 0, 0);

        float t0 = fmaxf(fmaxf(s[0], s[1]), fmaxf(s[2], s[3]));
        float t1 = fmaxf(fmaxf(s[4], s[5]), fmaxf(s[6], s[7]));
        float t2 = fmaxf(fmaxf(s[8], s[9]), fmaxf(s[10], s[11]));
        float t3 = fmaxf(fmaxf(s[12], s[13]), fmaxf(s[14], s[15]));
        float tmax = fmaxf(fmaxf(t0, t1), fmaxf(t2, t3));
        tmax = fmaxf(tmax, __shfl_xor(tmax, 32));

        if (!__all(tmax <= mrun)) {
            float mnew = fmaxf(mrun, tmax);
            float corr = fexp2(mrun - mnew);
            lrun *= corr;
            acc0 *= corr;
            acc1 *= corr;
            mrun = mnew;
        }

        float p[16];
        #pragma unroll
        for (int r = 0; r < 16; ++r) p[r] = fexp2(s[r] - mrun);
        float ts = ((p[0]+p[1]) + (p[2]+p[3])) + ((p[4]+p[5]) + (p[6]+p[7]))
                 + ((p[8]+p[9]) + (p[10]+p[11])) + ((p[12]+p[13]) + (p[14]+p[15]));
        ts += __shfl_xor(ts, 32);
        lrun += ts;

        int c01, c23, c45, c67, c89, cAB, cCD, cEF;
        asm("v_cvt_pk_bf16_f32 %0, %1, %2" : "=v"(c01) : "v"(p[0]),  "v"(p[1]));
        asm("v_cvt_pk_bf16_f32 %0, %1, %2" : "=v"(c23) : "v"(p[2]),  "v"(p[3]));
        asm("v_cvt_pk_bf16_f32 %0, %1, %2" : "=v"(c45) : "v"(p[4]),  "v"(p[5]));
        asm("v_cvt_pk_bf16_f32 %0, %1, %2" : "=v"(c67) : "v"(p[6]),  "v"(p[7]));
        asm("v_cvt_pk_bf16_f32 %0, %1, %2" : "=v"(c89) : "v"(p[8]),  "v"(p[9]));
        asm("v_cvt_pk_bf16_f32 %0, %1, %2" : "=v"(cAB) : "v"(p[10]), "v"(p[11]));
        asm("v_cvt_pk_bf16_f32 %0, %1, %2" : "=v"(cCD) : "v"(p[12]), "v"(p[13]));
        asm("v_cvt_pk_bf16_f32 %0, %1, %2" : "=v"(cEF) : "v"(p[14]), "v"(p[15]));

        uint2v s1 = __builtin_amdgcn_permlane32_swap(c45, c01, false, false);
        uint2v s2 = __builtin_amdgcn_permlane32_swap(c67, c23, false, false);
        uint2v s3 = __builtin_amdgcn_permlane32_swap(cCD, c89, false, false);
        uint2v s4 = __builtin_amdgcn_permlane32_swap(cEF, cAB, false, false);

        union { unsigned u[4]; short8 s; } B0, B1;
        B0.u[0] = s1[1]; B0.u[1] = s2[1]; B0.u[2] = s1[0]; B0.u[3] = s2[0];
        B1.u[0] = s3[1]; B1.u[1] = s4[1]; B1.u[2] = s3[0]; B1.u[3] = s4[0];

        acc0 = __builtin_amdgcn_mfma_f32_32x32x16_bf16(v00, B0.s, acc0, 0, 0, 0);
        acc0 = __builtin_amdgcn_mfma_f32_32x32x16_bf16(v01, B1.s, acc0, 0, 0, 0);
        acc1 = __builtin_amdgcn_mfma_f32_32x32x16_bf16(v10, B0.s, acc1, 0, 0, 0);
        acc1 = __builtin_amdgcn_mfma_f32_32x32x16_bf16(v11, B1.s, acc1, 0, 0, 0);
    }

    __shared__ float paccs[8][64][33];
    __shared__ float pml[8][2][32];
    #pragma unroll
    for (int r = 0; r < 16; ++r) {
        int c = (r & 3) + 8 * (r >> 2) + 4 * h;
        paccs[ws][c][l31]      = acc0[r];
        paccs[ws][c + 32][l31] = acc1[r];
    }
    if (lane < 32) { pml[ws][0][l31] = mrun; pml[ws][1][l31] = lrun; }
    __syncthreads();

    #pragma unroll
    for (int k = 0; k < 4; ++k) {
        int c = tid & 63;
        int n = (tid >> 6) + 8 * k;
        float M = -1e30f;
        #pragma unroll
        for (int w2 = 0; w2 < 8; ++w2) M = fmaxf(M, pml[w2][0][n]);
        float L = 0.f, oacc = 0.f;
        #pragma unroll
        for (int w2 = 0; w2 < 8; ++w2) {
            float e = fexp2(pml[w2][0][n] - M);
            L += pml[w2][1][n] * e;
            oacc += paccs[w2][c][n] * e;
        }
        size_t idx = ((size_t)(b * HW) + n0 + n) * C + c;
        float esv = es_t[idx] * cab[b * 64 + c] * sab[b * HW + n0 + n];
        cross_t[idx] = gma * oacc / L + esv;
    }
}

// ---------------- refine conv1x1 MFMA GEMM; inline gating + BN partial stats ----------------
// Weights come pre-converted to bf16 (rwb) -> no per-thread weight cvt.
__global__ __launch_bounds__(256) void refine_gemm_kernel(
    const float* __restrict__ cross_t, const float* __restrict__ es_t,
    const ushort* __restrict__ rwb, const float* __restrict__ rb,
    const float* __restrict__ gammap,
    const float* __restrict__ cab, const float* __restrict__ sab,
    float* __restrict__ y, float* __restrict__ part2) {
    const bool g0 = (gammap[0] == 0.f);
    int bid = blockIdx.x;
    int hwT = bid & 63, b = bid >> 6;
    int hw0 = hwT << 6;
    int t = threadIdx.x, lane = t & 63, wv = t >> 6;
    int colL = lane & 15, g = lane >> 4;
    int hw = hw0 + wv * 16 + colL;
    const float* sp = es_t + ((size_t)(b * HW) + hw) * C;
    const float* cp = cross_t + ((size_t)(b * HW) + hw) * C;
    const float* cgb = cab + b * 64;
    float gate = sab[b * HW + hw];
    __shared__ float redp[4][128][2];
    f32x4 acc[8] = {};
    #pragma unroll
    for (int ks = 0; ks < 4; ++ks) {
        f32x4 x1, x2;
        if (ks < 2 && !g0) {
            const float* src = cp + (ks & 1) * 32 + g * 8;
            x1 = *(const f32x4*)src;
            x2 = *(const f32x4*)(src + 4);
        } else {
            const float* src = sp + (ks & 1) * 32 + g * 8;
            const float* cg = cgb + (ks & 1) * 32 + g * 8;
            x1 = *(const f32x4*)src * *(const f32x4*)cg * gate;
            x2 = *(const f32x4*)(src + 4) * *(const f32x4*)(cg + 4) * gate;
        }
        short8 bf = cvt8(x1, x2);
        #pragma unroll
        for (int ot = 0; ot < 8; ++ot) {
            union { int4v v; short8 s; } af;
            af.v = *(const int4v*)(rwb + (size_t)(ot * 16 + colL) * TWOC + ks * 32 + g * 8);
            acc[ot] = __builtin_amdgcn_mfma_f32_16x16x32_bf16(af.s, bf, acc[ot], 0, 0, 0);
        }
    }
    // store + per-channel BN partials (sum, sumsq over this block's 64 hw)
    #pragma unroll
    for (int ot = 0; ot < 8; ++ot) {
        int o = ot * 16 + g * 4;
        #pragma unroll
        for (int r = 0; r < 4; ++r) {
            float v = acc[ot][r] + rb[o + r];
            y[((size_t)(b * TWOC + o + r) << 12) + hw0 + wv * 16 + colL] = v;
            float vq = v * v;
            #pragma unroll
            for (int d = 1; d < 16; d <<= 1) {
                v  += __shfl_xor(v, d);
                vq += __shfl_xor(vq, d);
            }
            if (colL == 0) { redp[wv][o + r][0] = v; redp[wv][o + r][1] = vq; }
        }
    }
    __syncthreads();
    if (t < 128) {
        float s  = redp[0][t][0] + redp[1][t][0] + redp[2][t][0] + redp[3][t][0];
        float s2 = redp[0][t][1] + redp[1][t][1] + redp[2][t][1] + redp[3][t][1];
        part2[t * 256 + bid] = s;
        part2[32768 + t * 256 + bid] = s2;
    }
}

// ---------------- BN apply + relu; each block reduces its channel's partials ----------------
__global__ __launch_bounds__(256) void bn_apply_kernel(float* __restrict__ y,
                                const float* __restrict__ part2,
                                const float* __restrict__ sc,
                                const float* __restrict__ bi) {
    int blk = blockIdx.x;              // 2048; block covers 1024 hw of one (b,o)
    int t = threadIdx.x;
    int o = (blk >> 2) & 127;
    float s  = part2[o * 256 + t];
    float s2 = part2[32768 + o * 256 + t];
    for (int d = 32; d > 0; d >>= 1) { s += __shfl_down(s, d); s2 += __shfl_down(s2, d); }
    __shared__ float rs[4], rs2[4], bc[2];
    if ((t & 63) == 0) { rs[t >> 6] = s; rs2[t >> 6] = s2; }
    __syncthreads();
    if (t == 0) {
        float S  = rs[0] + rs[1] + rs[2] + rs[3];
        float S2 = rs2[0] + rs2[1] + rs2[2] + rs2[3];
        float m = S * (1.f / (NB * HW));
        float var = S2 * (1.f / (NB * HW)) - m * m;
        bc[0] = m;
        bc[1] = rsqrtf(var + 1e-5f);
    }
    __syncthreads();
    float m = bc[0], rstd = bc[1], scale = sc[o], bias = bi[o];
    int i4 = blk * 256 + t;
    f32x4 v = *(const f32x4*)&y[(size_t)i4 * 4];
    #pragma unroll
    for (int j = 0; j < 4; ++j) v[j] = fmaxf((v[j] - m) * rstd * scale + bias, 0.f);
    *(f32x4*)&y[(size_t)i4 * 4] = v;
}

extern "C" void kernel_launch(void* const* d_in, const int* in_sizes, int n_in,
                              void* d_out, int out_size, void* d_ws, size_t ws_size,
                              hipStream_t stream) {
    const float* swin   = (const float*)d_in[0];
    const float* resnet = (const float*)d_in[1];
    const float* proj_w = (const float*)d_in[2];
    const float* proj_b = (const float*)d_in[3];
    const float* ca_w1  = (const float*)d_in[4];
    const float* ca_w2  = (const float*)d_in[5];
    const float* sa_w   = (const float*)d_in[6];
    const float* sa_b   = (const float*)d_in[7];
    const float* q_w    = (const float*)d_in[8];
    const float* q_b    = (const float*)d_in[9];
    const float* k_w    = (const float*)d_in[10];
    const float* k_b    = (const float*)d_in[11];
    const float* v_w    = (const float*)d_in[12];
    const float* v_b    = (const float*)d_in[13];
    const float* gamma  = (const float*)d_in[14];
    const float* ref_w  = (const float*)d_in[15];
    const float* ref_b  = (const float*)d_in[16];
    const float* bn_sc  = (const float*)d_in[17];
    const float* bn_bi  = (const float*)d_in[18];
    float* out = (float*)d_out;

    float* ws = (float*)d_ws;
    float* s_t    = ws;                  // 1048576
    float* r_t    = s_t + 1048576;       // 1048576
    float* cross_t= r_t + 1048576;       // 1048576
    float* part   = cross_t + 1048576;   // 32768
    float* cab    = part + 32768;        // 512
    float* avgc   = cab + 512;           // 32768
    float* maxc   = avgc + 32768;        // 32768
    float* sab    = maxc + 32768;        // 32768
    float* part2  = sab + 32768;         // 65536
    ushort* q_t   = (ushort*)(part2 + 65536); // 131072 us
    ushort* k_t   = q_t + 131072;             // 131072 us
    ushort* v_t   = k_t + 131072;             // 1048576 us
    ushort* rwb   = v_t + 1048576;            // 16384 us (refine weights bf16)

    // 1. proj + fused stats epilogue + refine-weight bf16 pre-conversion
    proj_gemm_kernel<<<512, 256, 0, stream>>>(swin, resnet, proj_w, proj_b, gamma,
                                              ref_w, s_t, r_t, part, avgc, maxc, rwb);
    // 2. merged channel-attn MLP + spatial-attn conv
    casa_kernel<<<129, 256, 0, stream>>>(part, ca_w1, ca_w2, cab, avgc, maxc,
                                         sa_w, sa_b, gamma, sab);
    // 3. q/k/v projections, gates inline (no-op when gamma==0)
    vqk_proj_kernel<<<256, 256, 0, stream>>>(s_t, r_t, v_w, v_b, q_w, q_b, k_w, k_b,
                                             gamma, cab, sab, v_t, q_t, k_t);
    // 4. flash cross-attention v3, es gated inline (no-op when gamma==0)
    cross_attn_mfma<<<NB * 128, 512, 0, stream>>>(q_t, k_t, v_t, s_t, gamma,
                                                  cab, sab, cross_t);
    // 5. refine -> d_out + BN partial stats (bf16 weights, inline gating)
    refine_gemm_kernel<<<256, 256, 0, stream>>>(cross_t, s_t, rwb, ref_b, gamma,
                                                cab, sab, out, part2);
    // 6. BN + relu in place (per-block partial reduce, no separate stats pass)
    bn_apply_kernel<<<NB * TWOC * HW / 1024, 256, 0, stream>>>(out, part2, bn_sc, bn_bi);
}

// Round 15
// 44.855 us; speedup vs baseline: 3.1019x; 1.0097x over previous
//
#include <hip/hip_runtime.h>
#include <hip/hip_bf16.h>
#include <math.h>

#define NB   4      // batch
#define CIN  128
#define C    64
#define HH   64
#define WW   64
#define HW   4096
#define C8   8
#define RR   4
#define TWOC 128
#define LOG2E 1.44269504088896340736f

typedef __attribute__((ext_vector_type(8))) short short8;
typedef __attribute__((ext_vector_type(4))) float f32x4;
typedef __attribute__((ext_vector_type(16))) float f32x16;
typedef __attribute__((ext_vector_type(4))) int int4v;
typedef __attribute__((ext_vector_type(2))) unsigned uint2v;

__device__ inline ushort f2bf(float f) {
    union { float f; unsigned u; } x{ f };
    unsigned r = x.u + 0x7FFFu + ((x.u >> 16) & 1u);   // RNE
    return (ushort)(r >> 16);
}

// hazard-safe HW exp2 (TRANS op via intrinsic so the backend inserts wait-states)
__device__ inline float fexp2(float x) { return __builtin_amdgcn_exp2f(x); }

// pack 8 f32 -> 8 bf16 (RNE) as a short8 MFMA fragment
__device__ inline short8 cvt8(f32x4 a, f32x4 b) {
    union { int i[4]; short8 s; } u;
    asm("v_cvt_pk_bf16_f32 %0, %1, %2" : "=v"(u.i[0]) : "v"(a[0]), "v"(a[1]));
    asm("v_cvt_pk_bf16_f32 %0, %1, %2" : "=v"(u.i[1]) : "v"(a[2]), "v"(a[3]));
    asm("v_cvt_pk_bf16_f32 %0, %1, %2" : "=v"(u.i[2]) : "v"(b[0]), "v"(b[1]));
    asm("v_cvt_pk_bf16_f32 %0, %1, %2" : "=v"(u.i[3]) : "v"(b[2]), "v"(b[3]));
    return u.s;
}

// ---------------- proj conv1x1 MFMA GEMM + fused stats epilogue ----------------
// Prologue pre-converts refine weights to bf16; at gamma==0 it FOLDS the two
// weight halves (w1+w2) into columns [0,64) since both refine inputs are the
// same gated-s vector -> refine becomes a 64-col GEMM.
__global__ __launch_bounds__(256) void proj_gemm_kernel(
    const float* __restrict__ sw, const float* __restrict__ rn,
    const float* __restrict__ w, const float* __restrict__ bias,
    const float* __restrict__ gammap, const float* __restrict__ rw,
    float* __restrict__ s_t, float* __restrict__ r_t,
    float* __restrict__ part, float* __restrict__ avgc, float* __restrict__ maxc,
    ushort* __restrict__ rwb) {
    int bid = blockIdx.x;
    int t = threadIdx.x;
    const bool g0 = (gammap[0] == 0.f);
    // refine-weight bf16 pre-conversion: 512 blocks x 32 floats = 16384
    if (t < 32) {
        int idx = bid * 32 + t;
        int o = idx >> 7, c = idx & 127;
        float v = rw[idx];
        if (g0 && c < 64) v += rw[o * 128 + 64 + c];   // fold W2 into W1
        rwb[idx] = f2bf(v);
    }

    int hwT = bid & 63;
    int b   = (bid >> 6) & 3;
    int img = bid >> 8;
    if (img == 1 && g0) return;
    int hw0 = hwT << 6;
    const float* x = (img ? rn : sw) + (size_t)b * CIN * HW + hw0;
    float* y = (img ? r_t : s_t) + (size_t)b * HW * C;

    __shared__ ushort xt[64 * 132];   // [hw][128c + 4 pad]
    __shared__ float redc[4][64];
    {
        // pair-staging: two adjacent channels are LDS-contiguous -> 1 cvt_pk + b32 store
        int hwl = t & 63, cq = t >> 6;
        #pragma unroll
        for (int i = 0; i < 16; ++i) {
            int c = cq * 32 + i * 2;
            float a  = x[(size_t)c * HW + hwl];
            float b2 = x[(size_t)(c + 1) * HW + hwl];
            int pk;
            asm("v_cvt_pk_bf16_f32 %0, %1, %2" : "=v"(pk) : "v"(a), "v"(b2));
            *(unsigned*)&xt[hwl * 132 + c] = (unsigned)pk;
        }
    }
    __syncthreads();

    int lane = t & 63, wv = t >> 6;
    int colL = lane & 15, g = lane >> 4;
    int hwsub = wv << 4;
    f32x4 acc[4] = {};
    #pragma unroll
    for (int ks = 0; ks < 4; ++ks) {
        const ushort* ap = &xt[(hwsub + colL) * 132 + ks * 32 + g * 8];
        union { uint2 u2[2]; short8 s; } af;
        af.u2[0] = *(const uint2*)ap;
        af.u2[1] = *(const uint2*)(ap + 4);
        #pragma unroll
        for (int ot = 0; ot < 4; ++ot) {
            const float* wp = w + (size_t)(ot * 16 + colL) * CIN + ks * 32 + g * 8;
            short8 bf = cvt8(*(const f32x4*)wp, *(const f32x4*)(wp + 4));
            acc[ot] = __builtin_amdgcn_mfma_f32_16x16x32_bf16(af.s, bf, acc[ot], 0, 0, 0);
        }
    }

    // store + in-register stats
    float rowsum[4], rowmax[4], colsum[4];
    #pragma unroll
    for (int r = 0; r < 4; ++r) { rowsum[r] = 0.f; rowmax[r] = -1e30f; }
    #pragma unroll
    for (int ot = 0; ot < 4; ++ot) colsum[ot] = 0.f;
    #pragma unroll
    for (int ot = 0; ot < 4; ++ot) {
        float bb = bias[ot * 16 + colL];
        #pragma unroll
        for (int r = 0; r < 4; ++r) {
            float v = acc[ot][r] + bb;
            y[(size_t)(hw0 + hwsub + g * 4 + r) * C + ot * 16 + colL] = v;
            rowsum[r] += v;
            rowmax[r] = fmaxf(rowmax[r], v);
            colsum[ot] += v;
        }
    }
    // per-hw reduce over channels (16 colL lanes within g-group)
    #pragma unroll
    for (int d = 1; d < 16; d <<= 1) {
        #pragma unroll
        for (int r = 0; r < 4; ++r) {
            rowsum[r] += __shfl_xor(rowsum[r], d);
            rowmax[r] = fmaxf(rowmax[r], __shfl_xor(rowmax[r], d));
        }
    }
    if (colL == 0) {
        int ob = (img * 4 + b) * HW + hw0 + hwsub + g * 4;
        #pragma unroll
        for (int r = 0; r < 4; ++r) {
            avgc[ob + r] = rowsum[r] * (1.f / C);
            maxc[ob + r] = rowmax[r];
        }
    }
    // per-channel reduce over hw: g (xor 16,32), then cross-wave via LDS
    #pragma unroll
    for (int d = 16; d < 64; d <<= 1) {
        #pragma unroll
        for (int ot = 0; ot < 4; ++ot) colsum[ot] += __shfl_xor(colsum[ot], d);
    }
    if (g == 0) {
        #pragma unroll
        for (int ot = 0; ot < 4; ++ot) redc[wv][ot * 16 + colL] = colsum[ot];
    }
    __syncthreads();
    if (t < 64)
        part[((size_t)(img * 4 + b) * 64 + hwT) * 64 + t] =
            redc[0][t] + redc[1][t] + redc[2][t] + redc[3][t];
}

// ---------------- merged channel-attn MLP + spatial-attn 7x7 conv ----------------
__global__ __launch_bounds__(256) void casa_kernel(
    const float* __restrict__ part, const float* __restrict__ w1,
    const float* __restrict__ w2, float* __restrict__ cab,
    const float* __restrict__ avgc, const float* __restrict__ maxc,
    const float* __restrict__ saw, const float* __restrict__ bsa,
    const float* __restrict__ gammap, float* __restrict__ sab) {
    int bid = blockIdx.x;
    int t = threadIdx.x;
    if (bid == 128) {
        __shared__ float avs[8][64];
        __shared__ float hsh[8][RR];
        #pragma unroll
        for (int it = 0; it < 2; ++it) {
            int idx = t + it * 256;
            int c = idx & 63, ib = idx >> 6;
            float avg = 0.f;
            for (int hwT = 0; hwT < 64; ++hwT)
                avg += part[((size_t)ib * 64 + hwT) * 64 + c];
            avs[ib][c] = avg * (1.f / HW);
        }
        __syncthreads();
        if (t < 32) {
            int ib2 = t >> 2, r = t & 3;
            float a = 0.f;
            for (int cc = 0; cc < C; ++cc) a += avs[ib2][cc] * w1[r * C + cc];
            hsh[ib2][r] = fmaxf(a, 0.f);
        }
        __syncthreads();
        #pragma unroll
        for (int it = 0; it < 2; ++it) {
            int idx = t + it * 256;
            int c = idx & 63, ib = idx >> 6;
            float a = 0.f;
            #pragma unroll
            for (int r = 0; r < RR; ++r) a += hsh[ib][r] * w2[c * RR + r];
            cab[ib * 64 + c] = 1.f / (1.f + __expf(-a));
        }
        return;
    }
    int img = bid >> 6;
    if (img == 1 && gammap[0] == 0.f) return;
    __shared__ float wsh[98];
    if (t < 98) wsh[t] = saw[t];
    __syncthreads();
    int idx = (bid & 63) * 256 + t;            // b*HW + hw
    int b = idx >> 12, hw = idx & 4095;
    int base = (img * 4 + b) * HW;
    int y0 = hw >> 6, x0 = hw & 63;
    float acc = bsa[0];
    for (int dy = -3; dy <= 3; ++dy) {
        int yy = y0 + dy; if (yy < 0 || yy >= HH) continue;
        for (int dx = -3; dx <= 3; ++dx) {
            int xx = x0 + dx; if (xx < 0 || xx >= WW) continue;
            int widx = (dy + 3) * 7 + (dx + 3);
            int p = base + yy * WW + xx;
            acc += avgc[p] * wsh[widx] + maxc[p] * wsh[49 + widx];
        }
    }
    sab[base + hw] = 1.f / (1.f + __expf(-acc));
}

// ---------------- fused q/k/v projections, gates applied inline ----------------
__global__ __launch_bounds__(256) void vqk_proj_kernel(
    const float* __restrict__ es, const float* __restrict__ er,
    const float* __restrict__ vw, const float* __restrict__ vbv,
    const float* __restrict__ qw, const float* __restrict__ qbv,
    const float* __restrict__ kw, const float* __restrict__ kbv,
    const float* __restrict__ gammap,
    const float* __restrict__ cab, const float* __restrict__ sab,
    ushort* __restrict__ v_t, ushort* __restrict__ q_t, ushort* __restrict__ k_t) {
    if (gammap[0] == 0.f) return;     // q/k/v only feed the attention path
    __shared__ float wsh[64][64];            // vw[c][cc]
    __shared__ float qsh[8][64], ksh[8][64]; // qw, kw
    int t = threadIdx.x;
    for (int i = t; i < 4096; i += 256) wsh[i >> 6][i & 63] = vw[i];
    for (int i = t; i < 512; i += 256) qsh[i >> 6][i & 63] = qw[i];
    for (int i = t; i < 512; i += 256) ksh[i >> 6][i & 63] = kw[i];
    __syncthreads();

    int bid = blockIdx.x;
    int hw = ((bid & 63) << 6) + (t & 63);
    int b  = bid >> 6;
    int qt = t >> 6;                 // quarter 0..3
    int c0 = qt << 4;
    const float* erp = er + (size_t)(b * HW + hw) * C;
    const float* esp = es + (size_t)(b * HW + hw) * C;
    const float* cas = cab + b * 64;           // img0 gates
    const float* car = cab + (4 + b) * 64;     // img1 gates
    float gs = sab[b * HW + hw];
    float gr = sab[(4 + b) * HW + hw];

    float va[16];
    #pragma unroll
    for (int j = 0; j < 16; ++j) va[j] = vbv[c0 + j];
    float qa[8], ka[8];
    #pragma unroll
    for (int o = 0; o < 8; ++o) { qa[o] = qbv[o]; ka[o] = kbv[o]; }

    #pragma unroll 4
    for (int i = 0; i < 16; ++i) {
        f32x4 xr = *(const f32x4*)(erp + i * 4) * *(const f32x4*)(car + i * 4) * gr;
        #pragma unroll
        for (int j = 0; j < 16; ++j) {
            const float* wr = &wsh[c0 + j][i * 4];
            va[j] += xr[0]*wr[0] + xr[1]*wr[1] + xr[2]*wr[2] + xr[3]*wr[3];
        }
        if (qt == 0) {
            f32x4 xs = *(const f32x4*)(esp + i * 4) * *(const f32x4*)(cas + i * 4) * gs;
            #pragma unroll
            for (int o = 0; o < 8; ++o) {
                const float* wr = &qsh[o][i * 4];
                qa[o] += xs[0]*wr[0] + xs[1]*wr[1] + xs[2]*wr[2] + xs[3]*wr[3];
            }
        } else if (qt == 3) {
            #pragma unroll
            for (int o = 0; o < 8; ++o) {
                const float* wr = &ksh[o][i * 4];
                ka[o] += xr[0]*wr[0] + xr[1]*wr[1] + xr[2]*wr[2] + xr[3]*wr[3];
            }
        }
    }

    #pragma unroll
    for (int j = 0; j < 16; ++j)
        v_t[((size_t)(b * C + c0 + j) << 12) + hw] = f2bf(va[j]);
    if (qt == 0) {
        union { ushort u[8]; int4v v; } qo;
        #pragma unroll
        for (int o = 0; o < 8; ++o) qo.u[o] = f2bf(qa[o] * LOG2E);
        *(int4v*)(q_t + (size_t)(b * HW + hw) * 8) = qo.v;
    } else if (qt == 3) {
        union { ushort u[8]; int4v v; } ko;
        #pragma unroll
        for (int o = 0; o < 8; ++o) ko.u[o] = f2bf(ka[o]);
        *(int4v*)(k_t + (size_t)(b * HW + hw) * 8) = ko.v;
    }
}

// ---------------- MFMA flash cross-attention v3: 32x32x16, permlane transpose ----------------
__global__ __launch_bounds__(512) void cross_attn_mfma(
    const ushort* __restrict__ q_t, const ushort* __restrict__ k_t,
    const ushort* __restrict__ v_t, const float* __restrict__ es_t,
    const float* __restrict__ gammap,
    const float* __restrict__ cab, const float* __restrict__ sab,
    float* __restrict__ cross_t)
{
    const float gma = gammap[0];
    if (gma == 0.f) return;
    const int tid  = threadIdx.x;
    const int lane = tid & 63;
    const int ws   = tid >> 6;                 // m-split 0..7
    const int b    = blockIdx.x >> 7;          // 128 n-tiles per batch
    const int n0   = (blockIdx.x & 127) << 5;
    const int l31  = lane & 31;
    const int h    = lane >> 5;

    short8 qf = short8(0);
    if (lane < 32) qf = *(const short8*)(q_t + ((size_t)(b * HW) + n0 + l31) * 8);

    f32x16 acc0 = (f32x16)(0.f), acc1 = (f32x16)(0.f);
    float mrun = -1e30f, lrun = 0.f;

    const ushort* kbase = k_t + (size_t)(b * HW) * 8;
    const ushort* vb0 = v_t + ((size_t)(b * C) + l31) * HW + 8 * h;
    const ushort* vb1 = v_t + ((size_t)(b * C) + 32 + l31) * HW + 8 * h;

    const int mbeg = ws << 9, mend = mbeg + 512;
    for (int m0 = mbeg; m0 < mend; m0 += 32) {
        short8 kf = short8(0);
        if (lane < 32) kf = *(const short8*)(kbase + ((size_t)(m0 + l31)) * 8);
        short8 v00 = *(const short8*)(vb0 + m0);
        short8 v01 = *(const short8*)(vb0 + m0 + 16);
        short8 v10 = *(const short8*)(vb1 + m0);
        short8 v11 = *(const short8*)(vb1 + m0 + 16);

        f32x16 s = __builtin_amdgcn_mfma_f32_32x32x16_bf16(kf, qf, (f32x16)(0.f), 0, 0, 0);

        float t0 = fmaxf(fmaxf(s[0], s[1]), fmaxf(s[2], s[3]));
        float t1 = fmaxf(fmaxf(s[4], s[5]), fmaxf(s[6], s[7]));
        float t2 = fmaxf(fmaxf(s[8], s[9]), fmaxf(s[10], s[11]));
        float t3 = fmaxf(fmaxf(s[12], s[13]), fmaxf(s[14], s[15]));
        float tmax = fmaxf(fmaxf(t0, t1), fmaxf(t2, t3));
        tmax = fmaxf(tmax, __shfl_xor(tmax, 32));

        if (!__all(tmax <= mrun)) {
            float mnew = fmaxf(mrun, tmax);
            float corr = fexp2(mrun - mnew);
            lrun *= corr;
            acc0 *= corr;
            acc1 *= corr;
            mrun = mnew;
        }

        float p[16];
        #pragma unroll
        for (int r = 0; r < 16; ++r) p[r] = fexp2(s[r] - mrun);
        float ts = ((p[0]+p[1]) + (p[2]+p[3])) + ((p[4]+p[5]) + (p[6]+p[7]))
                 + ((p[8]+p[9]) + (p[10]+p[11])) + ((p[12]+p[13]) + (p[14]+p[15]));
        ts += __shfl_xor(ts, 32);
        lrun += ts;

        int c01, c23, c45, c67, c89, cAB, cCD, cEF;
        asm("v_cvt_pk_bf16_f32 %0, %1, %2" : "=v"(c01) : "v"(p[0]),  "v"(p[1]));
        asm("v_cvt_pk_bf16_f32 %0, %1, %2" : "=v"(c23) : "v"(p[2]),  "v"(p[3]));
        asm("v_cvt_pk_bf16_f32 %0, %1, %2" : "=v"(c45) : "v"(p[4]),  "v"(p[5]));
        asm("v_cvt_pk_bf16_f32 %0, %1, %2" : "=v"(c67) : "v"(p[6]),  "v"(p[7]));
        asm("v_cvt_pk_bf16_f32 %0, %1, %2" : "=v"(c89) : "v"(p[8]),  "v"(p[9]));
        asm("v_cvt_pk_bf16_f32 %0, %1, %2" : "=v"(cAB) : "v"(p[10]), "v"(p[11]));
        asm("v_cvt_pk_bf16_f32 %0, %1, %2" : "=v"(cCD) : "v"(p[12]), "v"(p[13]));
        asm("v_cvt_pk_bf16_f32 %0, %1, %2" : "=v"(cEF) : "v"(p[14]), "v"(p[15]));

        uint2v s1 = __builtin_amdgcn_permlane32_swap(c45, c01, false, false);
        uint2v s2 = __builtin_amdgcn_permlane32_swap(c67, c23, false, false);
        uint2v s3 = __builtin_amdgcn_permlane32_swap(cCD, c89, false, false);
        uint2v s4 = __builtin_amdgcn_permlane32_swap(cEF, cAB, false, false);

        union { unsigned u[4]; short8 s; } B0, B1;
        B0.u[0] = s1[1]; B0.u[1] = s2[1]; B0.u[2] = s1[0]; B0.u[3] = s2[0];
        B1.u[0] = s3[1]; B1.u[1] = s4[1]; B1.u[2] = s3[0]; B1.u[3] = s4[0];

        acc0 = __builtin_amdgcn_mfma_f32_32x32x16_bf16(v00, B0.s, acc0, 0, 0, 0);
        acc0 = __builtin_amdgcn_mfma_f32_32x32x16_bf16(v01, B1.s, acc0, 0, 0, 0);
        acc1 = __builtin_amdgcn_mfma_f32_32x32x16_bf16(v10, B0.s, acc1, 0, 0, 0);
        acc1 = __builtin_amdgcn_mfma_f32_32x32x16_bf16(v11, B1.s, acc1, 0, 0, 0);
    }

    __shared__ float paccs[8][64][33];
    __shared__ float pml[8][2][32];
    #pragma unroll
    for (int r = 0; r < 16; ++r) {
        int c = (r & 3) + 8 * (r >> 2) + 4 * h;
        paccs[ws][c][l31]      = acc0[r];
        paccs[ws][c + 32][l31] = acc1[r];
    }
    if (lane < 32) { pml[ws][0][l31] = mrun; pml[ws][1][l31] = lrun; }
    __syncthreads();

    #pragma unroll
    for (int k = 0; k < 4; ++k) {
        int c = tid & 63;
        int n = (tid >> 6) + 8 * k;
        float M = -1e30f;
        #pragma unroll
        for (int w2 = 0; w2 < 8; ++w2) M = fmaxf(M, pml[w2][0][n]);
        float L = 0.f, oacc = 0.f;
        #pragma unroll
        for (int w2 = 0; w2 < 8; ++w2) {
            float e = fexp2(pml[w2][0][n] - M);
            L += pml[w2][1][n] * e;
            oacc += paccs[w2][c][n] * e;
        }
        size_t idx = ((size_t)(b * HW) + n0 + n) * C + c;
        float esv = es_t[idx] * cab[b * 64 + c] * sab[b * HW + n0 + n];
        cross_t[idx] = gma * oacc / L + esv;
    }
}

// ---------------- refine conv1x1 MFMA GEMM; inline gating + BN partial stats ----------------
// gamma==0: weights arrive pre-FOLDED (w1+w2 in cols [0,64)) -> 2 ks steps, 16 MFMA.
__global__ __launch_bounds__(256) void refine_gemm_kernel(
    const float* __restrict__ cross_t, const float* __restrict__ es_t,
    const ushort* __restrict__ rwb, const float* __restrict__ rb,
    const float* __restrict__ gammap,
    const float* __restrict__ cab, const float* __restrict__ sab,
    float* __restrict__ y, float* __restrict__ part2) {
    const bool g0 = (gammap[0] == 0.f);
    int bid = blockIdx.x;
    int hwT = bid & 63, b = bid >> 6;
    int hw0 = hwT << 6;
    int t = threadIdx.x, lane = t & 63, wv = t >> 6;
    int colL = lane & 15, g = lane >> 4;
    int hw = hw0 + wv * 16 + colL;
    const float* sp = es_t + ((size_t)(b * HW) + hw) * C;
    const float* cp = cross_t + ((size_t)(b * HW) + hw) * C;
    const float* cgb = cab + b * 64;
    float gate = sab[b * HW + hw];
    __shared__ float redp[4][128][2];
    f32x4 acc[8] = {};
    if (g0) {
        // 64-col GEMM with folded weights: input = gated s, ks in {0,1}
        #pragma unroll
        for (int ks = 0; ks < 2; ++ks) {
            const float* src = sp + ks * 32 + g * 8;
            const float* cg = cgb + ks * 32 + g * 8;
            f32x4 x1 = *(const f32x4*)src * *(const f32x4*)cg * gate;
            f32x4 x2 = *(const f32x4*)(src + 4) * *(const f32x4*)(cg + 4) * gate;
            short8 bf = cvt8(x1, x2);
            #pragma unroll
            for (int ot = 0; ot < 8; ++ot) {
                union { int4v v; short8 s; } af;
                af.v = *(const int4v*)(rwb + (size_t)(ot * 16 + colL) * TWOC + ks * 32 + g * 8);
                acc[ot] = __builtin_amdgcn_mfma_f32_16x16x32_bf16(af.s, bf, acc[ot], 0, 0, 0);
            }
        }
    } else {
        #pragma unroll
        for (int ks = 0; ks < 4; ++ks) {
            f32x4 x1, x2;
            if (ks < 2) {
                const float* src = cp + (ks & 1) * 32 + g * 8;
                x1 = *(const f32x4*)src;
                x2 = *(const f32x4*)(src + 4);
            } else {
                const float* src = sp + (ks & 1) * 32 + g * 8;
                const float* cg = cgb + (ks & 1) * 32 + g * 8;
                x1 = *(const f32x4*)src * *(const f32x4*)cg * gate;
                x2 = *(const f32x4*)(src + 4) * *(const f32x4*)(cg + 4) * gate;
            }
            short8 bf = cvt8(x1, x2);
            #pragma unroll
            for (int ot = 0; ot < 8; ++ot) {
                union { int4v v; short8 s; } af;
                af.v = *(const int4v*)(rwb + (size_t)(ot * 16 + colL) * TWOC + ks * 32 + g * 8);
                acc[ot] = __builtin_amdgcn_mfma_f32_16x16x32_bf16(af.s, bf, acc[ot], 0, 0, 0);
            }
        }
    }
    // store + per-channel BN partials (sum, sumsq over this block's 64 hw)
    #pragma unroll
    for (int ot = 0; ot < 8; ++ot) {
        int o = ot * 16 + g * 4;
        #pragma unroll
        for (int r = 0; r < 4; ++r) {
            float v = acc[ot][r] + rb[o + r];
            y[((size_t)(b * TWOC + o + r) << 12) + hw0 + wv * 16 + colL] = v;
            float vq = v * v;
            #pragma unroll
            for (int d = 1; d < 16; d <<= 1) {
                v  += __shfl_xor(v, d);
                vq += __shfl_xor(vq, d);
            }
            if (colL == 0) { redp[wv][o + r][0] = v; redp[wv][o + r][1] = vq; }
        }
    }
    __syncthreads();
    if (t < 128) {
        float s  = redp[0][t][0] + redp[1][t][0] + redp[2][t][0] + redp[3][t][0];
        float s2 = redp[0][t][1] + redp[1][t][1] + redp[2][t][1] + redp[3][t][1];
        part2[t * 256 + bid] = s;
        part2[32768 + t * 256 + bid] = s2;
    }
}

// ---------------- BN apply + relu; 512 blocks, each owns one (b,o) pair ----------------
__global__ __launch_bounds__(256) void bn_apply_kernel(float* __restrict__ y,
                                const float* __restrict__ part2,
                                const float* __restrict__ sc,
                                const float* __restrict__ bi) {
    int bo = blockIdx.x;               // 0..511: b = bo>>7, o = bo&127
    int t = threadIdx.x;
    int o = bo & 127;
    float s  = part2[o * 256 + t];
    float s2 = part2[32768 + o * 256 + t];
    for (int d = 32; d > 0; d >>= 1) { s += __shfl_down(s, d); s2 += __shfl_down(s2, d); }
    __shared__ float rs[4], rs2[4], bc[2];
    if ((t & 63) == 0) { rs[t >> 6] = s; rs2[t >> 6] = s2; }
    __syncthreads();
    if (t == 0) {
        float S  = rs[0] + rs[1] + rs[2] + rs[3];
        float S2 = rs2[0] + rs2[1] + rs2[2] + rs2[3];
        float m = S * (1.f / (NB * HW));
        float var = S2 * (1.f / (NB * HW)) - m * m;
        bc[0] = m;
        bc[1] = rsqrtf(var + 1e-5f);
    }
    __syncthreads();
    float m = bc[0], rstd = bc[1], scale = sc[o], bias = bi[o];
    f32x4* y4 = (f32x4*)y;
    #pragma unroll
    for (int k = 0; k < 4; ++k) {
        size_t i4 = (size_t)bo * 1024 + k * 256 + t;
        f32x4 v = y4[i4];
        #pragma unroll
        for (int j = 0; j < 4; ++j) v[j] = fmaxf((v[j] - m) * rstd * scale + bias, 0.f);
        y4[i4] = v;
    }
}

extern "C" void kernel_launch(void* const* d_in, const int* in_sizes, int n_in,
                              void* d_out, int out_size, void* d_ws, size_t ws_size,
                              hipStream_t stream) {
    const float* swin   = (const float*)d_in[0];
    const float* resnet = (const float*)d_in[1];
    const float* proj_w = (const float*)d_in[2];
    const float* proj_b = (const float*)d_in[3];
    const float* ca_w1  = (const float*)d_in[4];
    const float* ca_w2  = (const float*)d_in[5];
    const float* sa_w   = (const float*)d_in[6];
    const float* sa_b   = (const float*)d_in[7];
    const float* q_w    = (const float*)d_in[8];
    const float* q_b    = (const float*)d_in[9];
    const float* k_w    = (const float*)d_in[10];
    const float* k_b    = (const float*)d_in[11];
    const float* v_w    = (const float*)d_in[12];
    const float* v_b    = (const float*)d_in[13];
    const float* gamma  = (const float*)d_in[14];
    const float* ref_w  = (const float*)d_in[15];
    const float* ref_b  = (const float*)d_in[16];
    const float* bn_sc  = (const float*)d_in[17];
    const float* bn_bi  = (const float*)d_in[18];
    float* out = (float*)d_out;

    float* ws = (float*)d_ws;
    float* s_t    = ws;                  // 1048576
    float* r_t    = s_t + 1048576;       // 1048576
    float* cross_t= r_t + 1048576;       // 1048576
    float* part   = cross_t + 1048576;   // 32768
    float* cab    = part + 32768;        // 512
    float* avgc   = cab + 512;           // 32768
    float* maxc   = avgc + 32768;        // 32768
    float* sab    = maxc + 32768;        // 32768
    float* part2  = sab + 32768;         // 65536
    ushort* q_t   = (ushort*)(part2 + 65536); // 131072 us
    ushort* k_t   = q_t + 131072;             // 131072 us
    ushort* v_t   = k_t + 131072;             // 1048576 us
    ushort* rwb   = v_t + 1048576;            // 16384 us (refine weights bf16)

    // 1. proj + fused stats epilogue + refine-weight bf16 pre-conversion (folded at gamma==0)
    proj_gemm_kernel<<<512, 256, 0, stream>>>(swin, resnet, proj_w, proj_b, gamma,
                                              ref_w, s_t, r_t, part, avgc, maxc, rwb);
    // 2. merged channel-attn MLP + spatial-attn conv
    casa_kernel<<<129, 256, 0, stream>>>(part, ca_w1, ca_w2, cab, avgc, maxc,
                                         sa_w, sa_b, gamma, sab);
    // 3. q/k/v projections, gates inline (no-op when gamma==0)
    vqk_proj_kernel<<<256, 256, 0, stream>>>(s_t, r_t, v_w, v_b, q_w, q_b, k_w, k_b,
                                             gamma, cab, sab, v_t, q_t, k_t);
    // 4. flash cross-attention v3, es gated inline (no-op when gamma==0)
    cross_attn_mfma<<<NB * 128, 512, 0, stream>>>(q_t, k_t, v_t, s_t, gamma,
                                                  cab, sab, cross_t);
    // 5. refine -> d_out + BN partial stats (folded weights at gamma==0)
    refine_gemm_kernel<<<256, 256, 0, stream>>>(cross_t, s_t, rwb, ref_b, gamma,
                                                cab, sab, out, part2);
    // 6. BN + relu in place (512 blocks, one (b,o) pair each)
    bn_apply_kernel<<<512, 256, 0, stream>>>(out, part2, bn_sc, bn_bi);
}